// Round 9
// baseline (492.082 us; speedup 1.0000x reference)
//
#include <hip/hip_runtime.h>

// LSTM anomaly detector: B=4096, T=512, I=3, H=64 (4H=256 gates)
// R12 = R11 + decoder off the critical path:
//  - Decoder PRE-barrier (R8-verified placement): iter t computes out[t-1]
//    from the A-frags (still h_{t-1}), rotating wave (t-1)&3. Its 2 MFMAs
//    issue amid the gate MFMAs; latency hides under the activation tail.
//    No post-barrier straggler.
//  - Decoder single-plane fp16 (terminal projection, no recurrence
//    amplification; error ~4e-5 << 2^-10 output floor): 2 MFMAs, Dl dropped.
//  - OOF flush at chunk-START post-barrier (+ trailing sync to protect
//    slot 0); epilogue emits out[511] + final flush.
//  - Everything else R11 verbatim: fp16-pair W_hh (4 MFMA/tile), single RNE
//    fp16 h, exact fp32 x-path, gate-interleaved activations, 1 main
//    barrier/step, chunk staging machinery.

#define TLEN 512
#define TCHUNK 64
#define ROWS 16

typedef float    float4_t __attribute__((ext_vector_type(4)));
typedef _Float16 halfx8   __attribute__((ext_vector_type(8)));

#define INV2048 4.8828125e-4f

__device__ __forceinline__ float fexp2(float x){ return __builtin_amdgcn_exp2f(x); }
__device__ __forceinline__ float frcp (float x){ return __builtin_amdgcn_rcpf(x); }
__device__ __forceinline__ float sigm (float x){ return frcp(1.f + fexp2(-1.44269504f*x)); }
__device__ __forceinline__ float tanh_(float x){ return 1.f - 2.f*frcp(1.f + fexp2(2.88539008f*x)); }

__device__ __forceinline__ unsigned short hbits(_Float16 h){
  union { _Float16 h; unsigned short u; } x; x.h = h; return x.u;
}

// setup-only fp16 pair split (lo-plane scaled by 2048 to stay normal)
__device__ __forceinline__ void split8h(const float* v, halfx8& hi, halfx8& lo){
  #pragma unroll
  for (int j = 0; j < 8; j++){
    _Float16 h = (_Float16)v[j];
    hi[j] = h;
    lo[j] = (_Float16)((v[j] - (float)h) * 2048.0f);
  }
}

#define MFMA(a,b,c) __builtin_amdgcn_mfma_f32_16x16x32_f16((a),(b),(c),0,0,0)

// ---- LDS layout ----
// ushort region: h exchange (fp16, single plane), double-buffered, stride 72
#define HHI 0                 // 2 buf x [16 rows][72]
#define HS_SZ 2304
// float region:
#define XOF 0                 // [16 rows][196] fp32 raw x staging
#define XPK 3136              // [64 t][16 rows][4] packed {x0,x1,x2,0}
#define OOF 7232              // [16 rows][196] fp32 out staging
#define LF_SZ 10368

__global__ __launch_bounds__(256, 1)
void LSTMAnomalyDetector_kernel(
    const float* __restrict__ x,     const float* __restrict__ W_ih,
    const float* __restrict__ W_hh,  const float* __restrict__ b_ih,
    const float* __restrict__ b_hh,  const float* __restrict__ W_dec,
    const float* __restrict__ b_dec, float* __restrict__ out)
{
  __shared__ __align__(16) unsigned short HS[HS_SZ];
  __shared__ __align__(16) float          LF[LF_SZ];

  const int tid  = threadIdx.x;
  const int w    = tid >> 6;        // wave 0..3
  const int lane = tid & 63;
  const int q    = lane >> 4;       // quad 0..3
  const int lid  = lane & 15;
  const int b0   = blockIdx.x * ROWS;
  const int cw   = w*16 + lid;      // this lane's H-column

  // ---- resident weight fragments (B-operand: B[k=kt*32+q*8+j][n=lid]) ----
  halfx8 Bh[4][2], Bl[4][2];  // W_hh^T fp16 pair; tl = gate type (i,f,g,o)
  halfx8 Dh[2];               // decoder: W_dec^T fp16 single plane
  float  wi[4][3], bsum[4];   // fp32 x-path: W_ih row + (b_ih+b_hh)

  #pragma unroll
  for (int tl = 0; tl < 4; tl++){
    const int g = tl*64 + cw;                   // gate row (W_hh[256][64] row-major)
    #pragma unroll
    for (int kt = 0; kt < 2; kt++){
      const float* p = W_hh + g*64 + kt*32 + q*8;
      float v[8];
      #pragma unroll
      for (int j = 0; j < 8; j++) v[j] = p[j];
      split8h(v, Bh[tl][kt], Bl[tl][kt]);
    }
    wi[tl][0] = W_ih[g*3+0];
    wi[tl][1] = W_ih[g*3+1];
    wi[tl][2] = W_ih[g*3+2];
    bsum[tl]  = b_ih[g] + b_hh[g];
  }
  #pragma unroll
  for (int kt = 0; kt < 2; kt++){
    #pragma unroll
    for (int j = 0; j < 8; j++) Dh[kt][j] = (_Float16)0.f;
    if (lid < 3){
      const float* p = W_dec + lid*64 + kt*32 + q*8;
      #pragma unroll
      for (int j = 0; j < 8; j++) Dh[kt][j] = (_Float16)p[j];
    }
  }
  const float bdec = (lid < 3) ? b_dec[lid] : 0.f;

  // ---- state ----
  halfx8 ah0 = {}, ah1 = {};                  // h_{t-1} A-frags (fp16), h_{-1}=0
  float creg[4] = {0.f, 0.f, 0.f, 0.f};       // c for rows q*4+r @ col cw
  float4_t xp4[4];                            // fp32 x-part per gate, 4 rows

  auto loadx = [&](int d){
    #pragma unroll
    for (int r = 0; r < 4; r++){
      float4_t xv = *(const float4_t*)&LF[XPK + d*64 + (q*4+r)*4];
      #pragma unroll
      for (int tl = 0; tl < 4; tl++)
        xp4[tl][r] = fmaf(wi[tl][2], xv[2],
                      fmaf(wi[tl][1], xv[1],
                        fmaf(wi[tl][0], xv[0], bsum[tl])));
    }
  };

  // ---- preload + pack x chunk 0 ----
  #pragma unroll
  for (int s = 0; s < 3; s++){
    const int f = tid + 256*s;                 // 768 float4 = 16 rows x 48
    const int row = f/48; const int off = (f%48)*4;
    float4_t v = *(const float4_t*)(x + (size_t)(b0+row)*1536 + off);
    *(float4_t*)&LF[XOF + row*196 + off] = v;
  }
  __syncthreads();
  #pragma unroll
  for (int s = 0; s < 4; s++){
    const int p = tid + 256*s;                 // p = t*16 + row, 0..1023
    const float* xr = &LF[XOF + (p & 15)*196 + (p >> 4)*3];
    float4_t v = {xr[0], xr[1], xr[2], 0.f};
    *(float4_t*)&LF[XPK + p*4] = v;
  }
  __syncthreads();
  loadx(0);

  for (int t = 0; t < TLEN; ++t){
    const int dt = t & (TCHUNK-1);
    const int hb = (t & 1) * 1152;

    // ---- tile 0 (i-gate): c1 = xp-seed + h*Whi (K=64); c2 = h*Wlo*2048 ----
    float4_t c1 = xp4[0];
    c1 = MFMA(ah0, Bh[0][0], c1);
    c1 = MFMA(ah1, Bh[0][1], c1);
    float4_t c2 = {0.f,0.f,0.f,0.f};
    c2 = MFMA(ah0, Bl[0][0], c2);
    c2 = MFMA(ah1, Bl[0][1], c2);
    float4_t g0;
    #pragma unroll
    for (int r = 0; r < 4; r++) g0[r] = fmaf(c2[r], INV2048, c1[r]);
    float4_t ig;
    #pragma unroll
    for (int r = 0; r < 4; r++) ig[r] = sigm(g0[r]);

    // decoder for step t-1 PRE-barrier (A-frags still hold h_{t-1});
    // rotating wave; single fp16 plane; issues amid the gate MFMAs
    if (t > 0 && w == ((t-1) & 3)){
      float4_t d1 = {0.f,0.f,0.f,0.f};
      d1 = MFMA(ah0, Dh[0], d1);
      d1 = MFMA(ah1, Dh[1], d1);
      if (lid < 3){
        const int dto = (t-1) & (TCHUNK-1);
        #pragma unroll
        for (int r = 0; r < 4; r++)
          LF[OOF + (q*4+r)*196 + dto*3 + lid] = d1[r] + bdec;
      }
    }

    // ---- tile 1 (f-gate) ----
    c1 = xp4[1];
    c1 = MFMA(ah0, Bh[1][0], c1);
    c1 = MFMA(ah1, Bh[1][1], c1);
    c2 = (float4_t){0.f,0.f,0.f,0.f};
    c2 = MFMA(ah0, Bl[1][0], c2);
    c2 = MFMA(ah1, Bl[1][1], c2);
    float4_t g1;
    #pragma unroll
    for (int r = 0; r < 4; r++) g1[r] = fmaf(c2[r], INV2048, c1[r]);
    float4_t fg;
    #pragma unroll
    for (int r = 0; r < 4; r++) fg[r] = sigm(g1[r]);

    // ---- tile 2 (g-gate) ----
    c1 = xp4[2];
    c1 = MFMA(ah0, Bh[2][0], c1);
    c1 = MFMA(ah1, Bh[2][1], c1);
    c2 = (float4_t){0.f,0.f,0.f,0.f};
    c2 = MFMA(ah0, Bl[2][0], c2);
    c2 = MFMA(ah1, Bl[2][1], c2);
    float4_t g2;
    #pragma unroll
    for (int r = 0; r < 4; r++) g2[r] = fmaf(c2[r], INV2048, c1[r]);
    float4_t gg;
    #pragma unroll
    for (int r = 0; r < 4; r++) gg[r] = tanh_(g2[r]);

    // ---- tile 3 (o-gate) ----
    c1 = xp4[3];
    c1 = MFMA(ah0, Bh[3][0], c1);
    c1 = MFMA(ah1, Bh[3][1], c1);
    c2 = (float4_t){0.f,0.f,0.f,0.f};
    c2 = MFMA(ah0, Bl[3][0], c2);
    c2 = MFMA(ah1, Bl[3][1], c2);
    float4_t g3;
    #pragma unroll
    for (int r = 0; r < 4; r++) g3[r] = fmaf(c2[r], INV2048, c1[r]);

    // ---- tail: o-sigm, c/h update, fp16 cvt, h writes ----
    #pragma unroll
    for (int r = 0; r < 4; r++){
      const float og = sigm(g3[r]);
      creg[r] = fg[r]*creg[r] + ig[r]*gg[r];
      const float h = og * tanh_(creg[r]);
      const _Float16 h16 = (_Float16)h;        // RNE, unbiased
      const int m = q*4 + r;
      HS[HHI + hb + m*72 + cw] = hbits(h16);
    }

    // prefetch next step's x-part BEFORE the barrier
    if (dt != TCHUNK-1) loadx(dt+1);

    __syncthreads();   // the ONE main barrier per step

    // rebuild A-frags: 2 raw ds_read_b128, zero VALU
    {
      const unsigned short* ph = &HS[HHI + hb + lid*72 + q*8];
      ah0 = *(const halfx8*)&ph[0];
      ah1 = *(const halfx8*)&ph[32];
    }

    // chunk-start flush: OOF holds out[t-64 .. t-1] (slot 63 written this
    // iter pre-barrier; visible after the main barrier above)
    if (dt == 0 && t > 0){
      const int t0 = t - TCHUNK;
      #pragma unroll
      for (int s = 0; s < 3; s++){
        const int f = tid + 256*s;
        const int row = f/48; const int off = (f%48)*4;
        float4_t v = *(const float4_t*)&LF[OOF + row*196 + off];
        *(float4_t*)(out + (size_t)(b0+row)*1536 + t0*3 + off) = v;
      }
      __syncthreads();   // protect OOF slot 0 from next iter's decoder write
    }

    // chunk boundary: stage+pack next x chunk (post-barrier; XPK idle)
    if (dt == TCHUNK-1 && t + 1 < TLEN){
      #pragma unroll
      for (int s = 0; s < 3; s++){
        const int f = tid + 256*s;
        const int row = f/48; const int off = (f%48)*4;
        float4_t v = *(const float4_t*)(x + (size_t)(b0+row)*1536 + (t+1)*3 + off);
        *(float4_t*)&LF[XOF + row*196 + off] = v;
      }
      __syncthreads();
      #pragma unroll
      for (int s = 0; s < 4; s++){
        const int p = tid + 256*s;
        const float* xr = &LF[XOF + (p & 15)*196 + (p >> 4)*3];
        float4_t v = {xr[0], xr[1], xr[2], 0.f};
        *(float4_t*)&LF[XPK + p*4] = v;
      }
      __syncthreads();
      loadx(0);
    }
  }

  // ---- epilogue: decoder for h_511 -> OOF slot 63, then final flush ----
  if (w == 3){                                  // (512-1)&3
    float4_t d1 = {0.f,0.f,0.f,0.f};
    d1 = MFMA(ah0, Dh[0], d1);
    d1 = MFMA(ah1, Dh[1], d1);
    if (lid < 3){
      #pragma unroll
      for (int r = 0; r < 4; r++)
        LF[OOF + (q*4+r)*196 + 63*3 + lid] = d1[r] + bdec;
    }
  }
  __syncthreads();
  {
    const int t0 = TLEN - TCHUNK;
    #pragma unroll
    for (int s = 0; s < 3; s++){
      const int f = tid + 256*s;
      const int row = f/48; const int off = (f%48)*4;
      float4_t v = *(const float4_t*)&LF[OOF + row*196 + off];
      *(float4_t*)(out + (size_t)(b0+row)*1536 + t0*3 + off) = v;
    }
  }
}

extern "C" void kernel_launch(void* const* d_in, const int* in_sizes, int n_in,
                              void* d_out, int out_size, void* d_ws, size_t ws_size,
                              hipStream_t stream)
{
  const float* x     = (const float*)d_in[0];
  const float* W_ih  = (const float*)d_in[1];
  const float* W_hh  = (const float*)d_in[2];
  const float* b_ih  = (const float*)d_in[3];
  const float* b_hh  = (const float*)d_in[4];
  const float* W_dec = (const float*)d_in[5];
  const float* b_dec = (const float*)d_in[6];
  float* out = (float*)d_out;

  const int B = in_sizes[0] / (TLEN * 3);   // 4096
  const int blocks = B / ROWS;              // 256
  hipLaunchKernelGGL(LSTMAnomalyDetector_kernel, dim3(blocks), dim3(256), 0, stream,
                     x, W_ih, W_hh, b_ih, b_hh, W_dec, b_dec, out);
}

// Round 10
// 448.043 us; speedup vs baseline: 1.0983x; 1.0983x over previous
//
#include <hip/hip_runtime.h>

// LSTM anomaly detector: B=4096, T=512, I=3, H=64 (4H=256 gates)
// R13 = R11 chassis + serial-tail cuts:
//  - Decoder: R11 placement (post-barrier, wave 0) but single fp16 plane
//    (2 MFMAs; terminal projection, error ~4e-5 << 2^-10 output floor).
//  - Tile order o,f,i,g + incremental c-update: o/f/i sigms and fg*c partial
//    hide under later tiles' MFMAs; tail after last MFMA is just
//    merge -> tanh(g) -> fma -> tanh(c) -> mul -> cvt -> ds_write.
//  - Peeled loops: 63 branch-light hot steps + boundary step per chunk.
//  - Everything else R11 verbatim: fp16-pair W_hh (4 MFMA/tile), single RNE
//    fp16 h (2 ds_read_b128 rebuild), exact fp32 x-path prefetched, one main
//    barrier/step, double-buffered h, chunk staging machinery.

#define TLEN 512
#define TCHUNK 64
#define ROWS 16

typedef float    float4_t __attribute__((ext_vector_type(4)));
typedef _Float16 halfx8   __attribute__((ext_vector_type(8)));

#define INV2048 4.8828125e-4f

__device__ __forceinline__ float fexp2(float x){ return __builtin_amdgcn_exp2f(x); }
__device__ __forceinline__ float frcp (float x){ return __builtin_amdgcn_rcpf(x); }
__device__ __forceinline__ float sigm (float x){ return frcp(1.f + fexp2(-1.44269504f*x)); }
__device__ __forceinline__ float tanh_(float x){ return 1.f - 2.f*frcp(1.f + fexp2(2.88539008f*x)); }

__device__ __forceinline__ unsigned short hbits(_Float16 h){
  union { _Float16 h; unsigned short u; } x; x.h = h; return x.u;
}

// setup-only fp16 pair split (lo-plane scaled by 2048 to stay normal)
__device__ __forceinline__ void split8h(const float* v, halfx8& hi, halfx8& lo){
  #pragma unroll
  for (int j = 0; j < 8; j++){
    _Float16 h = (_Float16)v[j];
    hi[j] = h;
    lo[j] = (_Float16)((v[j] - (float)h) * 2048.0f);
  }
}

#define MFMA(a,b,c) __builtin_amdgcn_mfma_f32_16x16x32_f16((a),(b),(c),0,0,0)

// ---- LDS layout ----
// ushort region: h exchange (fp16, single plane), double-buffered, stride 72
#define HHI 0                 // 2 buf x [16 rows][72]
#define HS_SZ 2304
// float region:
#define XOF 0                 // [16 rows][196] fp32 raw x staging
#define XPK 3136              // [64 t][16 rows][4] packed {x0,x1,x2,0}
#define OOF 7232              // [16 rows][196] fp32 out staging
#define LF_SZ 10368

__global__ __launch_bounds__(256, 1)
void LSTMAnomalyDetector_kernel(
    const float* __restrict__ x,     const float* __restrict__ W_ih,
    const float* __restrict__ W_hh,  const float* __restrict__ b_ih,
    const float* __restrict__ b_hh,  const float* __restrict__ W_dec,
    const float* __restrict__ b_dec, float* __restrict__ out)
{
  __shared__ __align__(16) unsigned short HS[HS_SZ];
  __shared__ __align__(16) float          LF[LF_SZ];

  const int tid  = threadIdx.x;
  const int w    = tid >> 6;        // wave 0..3
  const int lane = tid & 63;
  const int q    = lane >> 4;       // quad 0..3
  const int lid  = lane & 15;
  const int b0   = blockIdx.x * ROWS;
  const int cw   = w*16 + lid;      // this lane's H-column

  // ---- resident weight fragments (B-operand: B[k=kt*32+q*8+j][n=lid]) ----
  halfx8 Bh[4][2], Bl[4][2];  // W_hh^T fp16 pair; tl = gate type (i,f,g,o)
  halfx8 Dh[2];               // decoder: W_dec^T fp16 single plane
  float  wi[4][3], bsum[4];   // fp32 x-path: W_ih row + (b_ih+b_hh)

  #pragma unroll
  for (int tl = 0; tl < 4; tl++){
    const int g = tl*64 + cw;                   // gate row (W_hh[256][64] row-major)
    #pragma unroll
    for (int kt = 0; kt < 2; kt++){
      const float* p = W_hh + g*64 + kt*32 + q*8;
      float v[8];
      #pragma unroll
      for (int j = 0; j < 8; j++) v[j] = p[j];
      split8h(v, Bh[tl][kt], Bl[tl][kt]);
    }
    wi[tl][0] = W_ih[g*3+0];
    wi[tl][1] = W_ih[g*3+1];
    wi[tl][2] = W_ih[g*3+2];
    bsum[tl]  = b_ih[g] + b_hh[g];
  }
  #pragma unroll
  for (int kt = 0; kt < 2; kt++){
    #pragma unroll
    for (int j = 0; j < 8; j++) Dh[kt][j] = (_Float16)0.f;
    if (lid < 3){
      const float* p = W_dec + lid*64 + kt*32 + q*8;
      #pragma unroll
      for (int j = 0; j < 8; j++) Dh[kt][j] = (_Float16)p[j];
    }
  }
  const float bdec = (lid < 3) ? b_dec[lid] : 0.f;

  // ---- state ----
  halfx8 ah0 = {}, ah1 = {};                  // h_{t-1} A-frags (fp16), h_{-1}=0
  float creg[4] = {0.f, 0.f, 0.f, 0.f};       // c for rows q*4+r @ col cw
  float4_t xp4[4];                            // fp32 x-part per gate, 4 rows

  auto loadx = [&](int d){
    #pragma unroll
    for (int r = 0; r < 4; r++){
      float4_t xv = *(const float4_t*)&LF[XPK + d*64 + (q*4+r)*4];
      #pragma unroll
      for (int tl = 0; tl < 4; tl++)
        xp4[tl][r] = fmaf(wi[tl][2], xv[2],
                      fmaf(wi[tl][1], xv[1],
                        fmaf(wi[tl][0], xv[0], bsum[tl])));
    }
  };

  // one LSTM step; caller controls loadx/boundary
  auto step = [&](int t, int dt, bool last){
    const int hb = (t & 1) * 1152;

    // ---- tile o (gate 3) ----
    float4_t c1 = xp4[3];
    c1 = MFMA(ah0, Bh[3][0], c1);
    c1 = MFMA(ah1, Bh[3][1], c1);
    float4_t c2 = {0.f,0.f,0.f,0.f};
    c2 = MFMA(ah0, Bl[3][0], c2);
    c2 = MFMA(ah1, Bl[3][1], c2);
    float4_t og;
    #pragma unroll
    for (int r = 0; r < 4; r++) og[r] = sigm(fmaf(c2[r], INV2048, c1[r]));

    // ---- tile f (gate 1) ----
    c1 = xp4[1];
    c1 = MFMA(ah0, Bh[1][0], c1);
    c1 = MFMA(ah1, Bh[1][1], c1);
    c2 = (float4_t){0.f,0.f,0.f,0.f};
    c2 = MFMA(ah0, Bl[1][0], c2);
    c2 = MFMA(ah1, Bl[1][1], c2);
    float4_t cp;
    #pragma unroll
    for (int r = 0; r < 4; r++){
      const float fg = sigm(fmaf(c2[r], INV2048, c1[r]));
      cp[r] = fg * creg[r];
    }

    // ---- tile i (gate 0) ----
    c1 = xp4[0];
    c1 = MFMA(ah0, Bh[0][0], c1);
    c1 = MFMA(ah1, Bh[0][1], c1);
    c2 = (float4_t){0.f,0.f,0.f,0.f};
    c2 = MFMA(ah0, Bl[0][0], c2);
    c2 = MFMA(ah1, Bl[0][1], c2);
    float4_t ig;
    #pragma unroll
    for (int r = 0; r < 4; r++) ig[r] = sigm(fmaf(c2[r], INV2048, c1[r]));

    // ---- tile g (gate 2) + tail ----
    c1 = xp4[2];
    c1 = MFMA(ah0, Bh[2][0], c1);
    c1 = MFMA(ah1, Bh[2][1], c1);
    c2 = (float4_t){0.f,0.f,0.f,0.f};
    c2 = MFMA(ah0, Bl[2][0], c2);
    c2 = MFMA(ah1, Bl[2][1], c2);
    #pragma unroll
    for (int r = 0; r < 4; r++){
      const float gg = tanh_(fmaf(c2[r], INV2048, c1[r]));
      creg[r] = fmaf(ig[r], gg, cp[r]);
      const float h = og[r] * tanh_(creg[r]);
      const _Float16 h16 = (_Float16)h;        // RNE, unbiased
      HS[HHI + hb + (q*4+r)*72 + cw] = hbits(h16);
    }

    // prefetch next step's x-part BEFORE the barrier
    if (!last) loadx(dt+1);

    __syncthreads();   // the ONE main barrier per step

    // rebuild A-frags: 2 raw ds_read_b128, zero VALU
    {
      const unsigned short* ph = &HS[HHI + hb + lid*72 + q*8];
      ah0 = *(const halfx8*)&ph[0];
      ah1 = *(const halfx8*)&ph[32];
    }

    // decoder on wave 0 (slack-absorbed): out_t -> OOF slot dt
    if (w == 0){
      float4_t d1 = {0.f,0.f,0.f,0.f};
      d1 = MFMA(ah0, Dh[0], d1);
      d1 = MFMA(ah1, Dh[1], d1);
      if (lid < 3){
        #pragma unroll
        for (int r = 0; r < 4; r++)
          LF[OOF + (q*4+r)*196 + dt*3 + lid] = d1[r] + bdec;
      }
    }
  };

  // ---- preload + pack x chunk 0 ----
  #pragma unroll
  for (int s = 0; s < 3; s++){
    const int f = tid + 256*s;                 // 768 float4 = 16 rows x 48
    const int row = f/48; const int off = (f%48)*4;
    float4_t v = *(const float4_t*)(x + (size_t)(b0+row)*1536 + off);
    *(float4_t*)&LF[XOF + row*196 + off] = v;
  }
  __syncthreads();
  #pragma unroll
  for (int s = 0; s < 4; s++){
    const int p = tid + 256*s;                 // p = t*16 + row, 0..1023
    const float* xr = &LF[XOF + (p & 15)*196 + (p >> 4)*3];
    float4_t v = {xr[0], xr[1], xr[2], 0.f};
    *(float4_t*)&LF[XPK + p*4] = v;
  }
  __syncthreads();
  loadx(0);

  for (int ck = 0; ck < TLEN/TCHUNK; ++ck){
    const int tb = ck * TCHUNK;

    // hot steps: no boundary branches
    for (int dt = 0; dt < TCHUNK-1; ++dt)
      step(tb + dt, dt, false);

    // boundary step (no loadx inside)
    step(tb + TCHUNK-1, TCHUNK-1, true);

    // ---- chunk boundary: flush out, stage+pack next x chunk ----
    __syncthreads();                           // OOF slot 63 visible
    #pragma unroll
    for (int s = 0; s < 3; s++){
      const int f = tid + 256*s;
      const int row = f/48; const int off = (f%48)*4;
      float4_t v = *(const float4_t*)&LF[OOF + row*196 + off];
      *(float4_t*)(out + (size_t)(b0+row)*1536 + tb*3 + off) = v;
    }
    if (ck + 1 < TLEN/TCHUNK){
      const int tn = tb + TCHUNK;
      #pragma unroll
      for (int s = 0; s < 3; s++){
        const int f = tid + 256*s;
        const int row = f/48; const int off = (f%48)*4;
        float4_t v = *(const float4_t*)(x + (size_t)(b0+row)*1536 + tn*3 + off);
        *(float4_t*)&LF[XOF + row*196 + off] = v;
      }
      __syncthreads();
      #pragma unroll
      for (int s = 0; s < 4; s++){
        const int p = tid + 256*s;
        const float* xr = &LF[XOF + (p & 15)*196 + (p >> 4)*3];
        float4_t v = {xr[0], xr[1], xr[2], 0.f};
        *(float4_t*)&LF[XPK + p*4] = v;
      }
    }
    __syncthreads();
    if (ck + 1 < TLEN/TCHUNK) loadx(0);
  }
}

extern "C" void kernel_launch(void* const* d_in, const int* in_sizes, int n_in,
                              void* d_out, int out_size, void* d_ws, size_t ws_size,
                              hipStream_t stream)
{
  const float* x     = (const float*)d_in[0];
  const float* W_ih  = (const float*)d_in[1];
  const float* W_hh  = (const float*)d_in[2];
  const float* b_ih  = (const float*)d_in[3];
  const float* b_hh  = (const float*)d_in[4];
  const float* W_dec = (const float*)d_in[5];
  const float* b_dec = (const float*)d_in[6];
  float* out = (float*)d_out;

  const int B = in_sizes[0] / (TLEN * 3);   // 4096
  const int blocks = B / ROWS;              // 256
  hipLaunchKernelGGL(LSTMAnomalyDetector_kernel, dim3(blocks), dim3(256), 0, stream,
                     x, W_ih, W_hh, b_ih, b_hh, W_dec, b_dec, out);
}

// Round 12
// 425.979 us; speedup vs baseline: 1.1552x; 1.0518x over previous
//
#include <hip/hip_runtime.h>

// LSTM anomaly detector: B=4096, T=512, I=3, H=64 (4H=256 gates)
// R14 = R13 + dedicated decoder wave:
//  - 5 waves (320 thr). Waves 0-3: recurrence (R13 verbatim math). Wave 4:
//    decoder only — per step t reads h_{t-1} from the INACTIVE H buffer
//    (double-buffered, valid through step t), 2 fp16 MFMAs, writes OOF.
//    Recurrence waves have an EMPTY post-barrier region (no straggler).
//  - OOF double-buffered by chunk parity: decoder writes OOF[k&1] while
//    waves 0-3 flush OOF[(k-1)&1] at dt==1 (disjoint at every step).
//    Epilogue: decode h_511, flush chunk 7.
//  - All __syncthreads outside w-conditionals (uniform across 5 waves).
//  - Else R13 verbatim: fp16-pair W_hh (4 MFMA/tile), tile order o,f,i,g,
//    incremental c-update, single RNE fp16 h, exact fp32 x-path prefetch,
//    one main barrier/step, chunk staging machinery.
// (Resubmission — previous round failed on infra, kernel never ran.)

#define TLEN 512
#define TCHUNK 64
#define ROWS 16

typedef float    float4_t __attribute__((ext_vector_type(4)));
typedef _Float16 halfx8   __attribute__((ext_vector_type(8)));

#define INV2048 4.8828125e-4f

__device__ __forceinline__ float fexp2(float x){ return __builtin_amdgcn_exp2f(x); }
__device__ __forceinline__ float frcp (float x){ return __builtin_amdgcn_rcpf(x); }
__device__ __forceinline__ float sigm (float x){ return frcp(1.f + fexp2(-1.44269504f*x)); }
__device__ __forceinline__ float tanh_(float x){ return 1.f - 2.f*frcp(1.f + fexp2(2.88539008f*x)); }

__device__ __forceinline__ unsigned short hbits(_Float16 h){
  union { _Float16 h; unsigned short u; } x; x.h = h; return x.u;
}

// setup-only fp16 pair split (lo-plane scaled by 2048 to stay normal)
__device__ __forceinline__ void split8h(const float* v, halfx8& hi, halfx8& lo){
  #pragma unroll
  for (int j = 0; j < 8; j++){
    _Float16 h = (_Float16)v[j];
    hi[j] = h;
    lo[j] = (_Float16)((v[j] - (float)h) * 2048.0f);
  }
}

#define MFMA(a,b,c) __builtin_amdgcn_mfma_f32_16x16x32_f16((a),(b),(c),0,0,0)

// ---- LDS layout ----
// ushort region: h exchange (fp16, single plane), double-buffered, stride 72
#define HHI 0                 // 2 buf x [16 rows][72]
#define HS_SZ 2304
// float region:
#define XOF 0                 // [16 rows][196] fp32 raw x staging
#define XPK 3136              // [64 t][16 rows][4] packed {x0,x1,x2,0}
#define OOF0 7232             // [16 rows][196] fp32 out staging, chunk-even
#define OOF1 10368            // [16 rows][196] fp32 out staging, chunk-odd
#define LF_SZ 13504

__global__ __launch_bounds__(320, 1)
void LSTMAnomalyDetector_kernel(
    const float* __restrict__ x,     const float* __restrict__ W_ih,
    const float* __restrict__ W_hh,  const float* __restrict__ b_ih,
    const float* __restrict__ b_hh,  const float* __restrict__ W_dec,
    const float* __restrict__ b_dec, float* __restrict__ out)
{
  __shared__ __align__(16) unsigned short HS[HS_SZ];
  __shared__ __align__(16) float          LF[LF_SZ];

  const int tid  = threadIdx.x;
  const int w    = tid >> 6;        // wave 0..4
  const int lane = tid & 63;
  const int q    = lane >> 4;       // quad 0..3
  const int lid  = lane & 15;
  const int b0   = blockIdx.x * ROWS;
  const int cw   = (w & 3)*16 + lid; // recurrence lane's H-column (w<4)

  // ---- resident weight fragments (B-operand: B[k=kt*32+q*8+j][n=lid]) ----
  halfx8 Bh[4][2], Bl[4][2];  // W_hh^T fp16 pair; tl = gate type (i,f,g,o)
  halfx8 Dh[2];               // decoder: W_dec^T fp16 single plane (wave 4)
  float  wi[4][3], bsum[4];   // fp32 x-path: W_ih row + (b_ih+b_hh)

  if (w < 4){
    #pragma unroll
    for (int tl = 0; tl < 4; tl++){
      const int g = tl*64 + cw;                 // gate row (W_hh[256][64] row-major)
      #pragma unroll
      for (int kt = 0; kt < 2; kt++){
        const float* p = W_hh + g*64 + kt*32 + q*8;
        float v[8];
        #pragma unroll
        for (int j = 0; j < 8; j++) v[j] = p[j];
        split8h(v, Bh[tl][kt], Bl[tl][kt]);
      }
      wi[tl][0] = W_ih[g*3+0];
      wi[tl][1] = W_ih[g*3+1];
      wi[tl][2] = W_ih[g*3+2];
      bsum[tl]  = b_ih[g] + b_hh[g];
    }
  } else {
    #pragma unroll
    for (int kt = 0; kt < 2; kt++){
      #pragma unroll
      for (int j = 0; j < 8; j++) Dh[kt][j] = (_Float16)0.f;
      if (lid < 3){
        const float* p = W_dec + lid*64 + kt*32 + q*8;
        #pragma unroll
        for (int j = 0; j < 8; j++) Dh[kt][j] = (_Float16)p[j];
      }
    }
  }
  const float bdec = (lid < 3) ? b_dec[lid] : 0.f;

  // ---- state (recurrence waves) ----
  halfx8 ah0 = {}, ah1 = {};                  // h_{t-1} A-frags (fp16), h_{-1}=0
  float creg[4] = {0.f, 0.f, 0.f, 0.f};       // c for rows q*4+r @ col cw
  float4_t xp4[4];                            // fp32 x-part per gate, 4 rows

  auto loadx = [&](int d){
    #pragma unroll
    for (int r = 0; r < 4; r++){
      float4_t xv = *(const float4_t*)&LF[XPK + d*64 + (q*4+r)*4];
      #pragma unroll
      for (int tl = 0; tl < 4; tl++)
        xp4[tl][r] = fmaf(wi[tl][2], xv[2],
                      fmaf(wi[tl][1], xv[1],
                        fmaf(wi[tl][0], xv[0], bsum[tl])));
    }
  };

  // ---- preload + pack x chunk 0 ----
  if (w < 4){
    #pragma unroll
    for (int s = 0; s < 3; s++){
      const int f = tid + 256*s;               // 768 float4 = 16 rows x 48
      const int row = f/48; const int off = (f%48)*4;
      float4_t v = *(const float4_t*)(x + (size_t)(b0+row)*1536 + off);
      *(float4_t*)&LF[XOF + row*196 + off] = v;
    }
  }
  __syncthreads();
  if (w < 4){
    #pragma unroll
    for (int s = 0; s < 4; s++){
      const int p = tid + 256*s;               // p = t*16 + row, 0..1023
      const float* xr = &LF[XOF + (p & 15)*196 + (p >> 4)*3];
      float4_t v = {xr[0], xr[1], xr[2], 0.f};
      *(float4_t*)&LF[XPK + p*4] = v;
    }
  }
  __syncthreads();
  if (w < 4) loadx(0);

  for (int t = 0; t < TLEN; ++t){
    const int dt = t & (TCHUNK-1);
    const int hb = (t & 1) * 1152;

    if (w < 4){
      // ---- tile o (gate 3) ----
      float4_t c1 = xp4[3];
      c1 = MFMA(ah0, Bh[3][0], c1);
      c1 = MFMA(ah1, Bh[3][1], c1);
      float4_t c2 = {0.f,0.f,0.f,0.f};
      c2 = MFMA(ah0, Bl[3][0], c2);
      c2 = MFMA(ah1, Bl[3][1], c2);
      float4_t og;
      #pragma unroll
      for (int r = 0; r < 4; r++) og[r] = sigm(fmaf(c2[r], INV2048, c1[r]));

      // ---- tile f (gate 1) ----
      c1 = xp4[1];
      c1 = MFMA(ah0, Bh[1][0], c1);
      c1 = MFMA(ah1, Bh[1][1], c1);
      c2 = (float4_t){0.f,0.f,0.f,0.f};
      c2 = MFMA(ah0, Bl[1][0], c2);
      c2 = MFMA(ah1, Bl[1][1], c2);
      float4_t cp;
      #pragma unroll
      for (int r = 0; r < 4; r++){
        const float fg = sigm(fmaf(c2[r], INV2048, c1[r]));
        cp[r] = fg * creg[r];
      }

      // ---- tile i (gate 0) ----
      c1 = xp4[0];
      c1 = MFMA(ah0, Bh[0][0], c1);
      c1 = MFMA(ah1, Bh[0][1], c1);
      c2 = (float4_t){0.f,0.f,0.f,0.f};
      c2 = MFMA(ah0, Bl[0][0], c2);
      c2 = MFMA(ah1, Bl[0][1], c2);
      float4_t ig;
      #pragma unroll
      for (int r = 0; r < 4; r++) ig[r] = sigm(fmaf(c2[r], INV2048, c1[r]));

      // ---- tile g (gate 2) + tail ----
      c1 = xp4[2];
      c1 = MFMA(ah0, Bh[2][0], c1);
      c1 = MFMA(ah1, Bh[2][1], c1);
      c2 = (float4_t){0.f,0.f,0.f,0.f};
      c2 = MFMA(ah0, Bl[2][0], c2);
      c2 = MFMA(ah1, Bl[2][1], c2);
      #pragma unroll
      for (int r = 0; r < 4; r++){
        const float gg = tanh_(fmaf(c2[r], INV2048, c1[r]));
        creg[r] = fmaf(ig[r], gg, cp[r]);
        const float h = og[r] * tanh_(creg[r]);
        const _Float16 h16 = (_Float16)h;      // RNE, unbiased
        HS[HHI + hb + (q*4+r)*72 + cw] = hbits(h16);
      }

      // prefetch next step's x-part BEFORE the barrier
      if (dt != TCHUNK-1) loadx(dt+1);
    } else {
      // ---- decoder wave: decode h_{t-1} from the INACTIVE buffer ----
      if (t > 0){
        const int hbp = (1 - (t & 1)) * 1152;
        const unsigned short* ph = &HS[HHI + hbp + lid*72 + q*8];
        halfx8 dh0 = *(const halfx8*)&ph[0];
        halfx8 dh1 = *(const halfx8*)&ph[32];
        float4_t d1 = {0.f,0.f,0.f,0.f};
        d1 = MFMA(dh0, Dh[0], d1);
        d1 = MFMA(dh1, Dh[1], d1);
        if (lid < 3){
          const int tp  = t - 1;
          const int oof = OOF0 + ((tp >> 6) & 1) * 3136;
          const int dto = tp & (TCHUNK-1);
          #pragma unroll
          for (int r = 0; r < 4; r++)
            LF[oof + (q*4+r)*196 + dto*3 + lid] = d1[r] + bdec;
        }
      }
    }

    __syncthreads();   // the ONE main barrier per step

    if (w < 4){
      // rebuild A-frags: 2 raw ds_read_b128, zero VALU
      const unsigned short* ph = &HS[HHI + hb + lid*72 + q*8];
      ah0 = *(const halfx8*)&ph[0];
      ah1 = *(const halfx8*)&ph[32];

      // flush previous chunk's OOF once per chunk (slack slot; disjoint
      // buffer from the one the decoder wave is currently writing)
      if (dt == 1 && t > TCHUNK){
        const int ckf = (t >> 6) - 1;
        const int oof = OOF0 + (ckf & 1) * 3136;
        const int t0  = ckf * TCHUNK;
        #pragma unroll
        for (int s = 0; s < 3; s++){
          const int f = tid + 256*s;
          const int row = f/48; const int off = (f%48)*4;
          float4_t v = *(const float4_t*)&LF[oof + row*196 + off];
          *(float4_t*)(out + (size_t)(b0+row)*1536 + t0*3 + off) = v;
        }
      }
    }

    // chunk boundary: stage+pack next x chunk (uniform barrier structure)
    if (dt == TCHUNK-1){
      if (t + 1 < TLEN){
        if (w < 4){
          #pragma unroll
          for (int s = 0; s < 3; s++){
            const int f = tid + 256*s;
            const int row = f/48; const int off = (f%48)*4;
            float4_t v = *(const float4_t*)(x + (size_t)(b0+row)*1536 + (t+1)*3 + off);
            *(float4_t*)&LF[XOF + row*196 + off] = v;
          }
        }
        __syncthreads();
        if (w < 4){
          #pragma unroll
          for (int s = 0; s < 4; s++){
            const int p = tid + 256*s;
            const float* xr = &LF[XOF + (p & 15)*196 + (p >> 4)*3];
            float4_t v = {xr[0], xr[1], xr[2], 0.f};
            *(float4_t*)&LF[XPK + p*4] = v;
          }
        }
      }
      __syncthreads();
      if (w < 4 && t + 1 < TLEN) loadx(0);
    }
  }

  // ---- epilogue: decode h_511, flush last chunk ----
  if (w == 4){
    const int hbp = ((TLEN-1) & 1) * 1152;     // buffer holding h_511
    const unsigned short* ph = &HS[HHI + hbp + lid*72 + q*8];
    halfx8 dh0 = *(const halfx8*)&ph[0];
    halfx8 dh1 = *(const halfx8*)&ph[32];
    float4_t d1 = {0.f,0.f,0.f,0.f};
    d1 = MFMA(dh0, Dh[0], d1);
    d1 = MFMA(dh1, Dh[1], d1);
    if (lid < 3){
      const int oof = OOF0 + (((TLEN-1) >> 6) & 1) * 3136;
      #pragma unroll
      for (int r = 0; r < 4; r++)
        LF[oof + (q*4+r)*196 + 63*3 + lid] = d1[r] + bdec;
    }
  }
  __syncthreads();
  if (w < 4){
    const int ckf = (TLEN >> 6) - 1;
    const int oof = OOF0 + (ckf & 1) * 3136;
    const int t0  = ckf * TCHUNK;
    #pragma unroll
    for (int s = 0; s < 3; s++){
      const int f = tid + 256*s;
      const int row = f/48; const int off = (f%48)*4;
      float4_t v = *(const float4_t*)&LF[oof + row*196 + off];
      *(float4_t*)(out + (size_t)(b0+row)*1536 + t0*3 + off) = v;
    }
  }
}

extern "C" void kernel_launch(void* const* d_in, const int* in_sizes, int n_in,
                              void* d_out, int out_size, void* d_ws, size_t ws_size,
                              hipStream_t stream)
{
  const float* x     = (const float*)d_in[0];
  const float* W_ih  = (const float*)d_in[1];
  const float* W_hh  = (const float*)d_in[2];
  const float* b_ih  = (const float*)d_in[3];
  const float* b_hh  = (const float*)d_in[4];
  const float* W_dec = (const float*)d_in[5];
  const float* b_dec = (const float*)d_in[6];
  float* out = (float*)d_out;

  const int B = in_sizes[0] / (TLEN * 3);   // 4096
  const int blocks = B / ROWS;              // 256
  hipLaunchKernelGGL(LSTMAnomalyDetector_kernel, dim3(blocks), dim3(320), 0, stream,
                     x, W_ih, W_hh, b_ih, b_hh, W_dec, b_dec, out);
}